// Round 1
// baseline (395.586 us; speedup 1.0000x reference)
//
#include <hip/hip_runtime.h>

#define VOCAB 50257
#define BATCH 1024
#define SEQ   512
#define H1    1024
#define H2    512
#define NC    20

// ---------------------------------------------------------------------------
// Kernel 1: h1[b,:] = relu(b1 + sum_s W1[x[b,s],:])
// One block per batch row, 256 threads, each thread owns one float4 column
// slot (4 consecutive cols). Per token the block reads the whole 4KB W1 row,
// perfectly coalesced (lane i reads float4 i).
// ---------------------------------------------------------------------------
__global__ __launch_bounds__(256) void k1_gather_sum(
    const int* __restrict__ x, const float* __restrict__ W1,
    const float* __restrict__ b1, float* __restrict__ h1) {
    const int row = blockIdx.x;
    const int tid = threadIdx.x;

    __shared__ int toks[SEQ];
    for (int i = tid; i < SEQ; i += 256) toks[i] = x[row * SEQ + i];
    __syncthreads();

    float4 acc = make_float4(0.f, 0.f, 0.f, 0.f);
#pragma unroll 8
    for (int s = 0; s < SEQ; ++s) {
        const int t = toks[s];  // LDS broadcast (uniform) — conflict-free
        const float4 w = ((const float4*)(W1 + (size_t)t * H1))[tid];
        acc.x += w.x; acc.y += w.y; acc.z += w.z; acc.w += w.w;
    }

    const float4 bb = ((const float4*)b1)[tid];
    float4 r;
    r.x = fmaxf(acc.x + bb.x, 0.f);
    r.y = fmaxf(acc.y + bb.y, 0.f);
    r.z = fmaxf(acc.z + bb.z, 0.f);
    r.w = fmaxf(acc.w + bb.w, 0.f);
    ((float4*)h1)[row * (H1 / 4) + tid] = r;
}

// ---------------------------------------------------------------------------
// Kernel 2: h2 = relu(h1 @ W2 + b2)   [1024,1024] @ [1024,512]
// Block = 128 threads; each thread owns one float4 col slot of W2's 512 cols.
// 4 batch rows per block (staged in LDS, broadcast reads), so W2 is read
// 256x total = 537 MB, L2-resident.
// ---------------------------------------------------------------------------
__global__ __launch_bounds__(128) void k2_gemm_relu(
    const float* __restrict__ h1, const float* __restrict__ W2,
    const float* __restrict__ b2, float* __restrict__ h2) {
    __shared__ float hs[4][H1];
    const int r0 = blockIdx.x * 4;
    const int tid = threadIdx.x;

    // stage 4 rows of h1 (16 KB) into LDS
    for (int i = tid; i < 4 * H1 / 4; i += 128)
        ((float4*)hs)[i] = ((const float4*)(h1 + (size_t)r0 * H1))[i];
    __syncthreads();

    float4 a0 = make_float4(0.f, 0.f, 0.f, 0.f);
    float4 a1 = a0, a2 = a0, a3 = a0;

#pragma unroll 4
    for (int k = 0; k < H1; ++k) {
        const float4 w = ((const float4*)(W2 + (size_t)k * H2))[tid];
        const float s0 = hs[0][k], s1 = hs[1][k], s2 = hs[2][k], s3 = hs[3][k];
        a0.x += s0 * w.x; a0.y += s0 * w.y; a0.z += s0 * w.z; a0.w += s0 * w.w;
        a1.x += s1 * w.x; a1.y += s1 * w.y; a1.z += s1 * w.z; a1.w += s1 * w.w;
        a2.x += s2 * w.x; a2.y += s2 * w.y; a2.z += s2 * w.z; a2.w += s2 * w.w;
        a3.x += s3 * w.x; a3.y += s3 * w.y; a3.z += s3 * w.z; a3.w += s3 * w.w;
    }

    const float4 bb = ((const float4*)b2)[tid];
    float4 o;
#define STORE_ROW(j, aj)                                                     \
    o.x = fmaxf(aj.x + bb.x, 0.f); o.y = fmaxf(aj.y + bb.y, 0.f);            \
    o.z = fmaxf(aj.z + bb.z, 0.f); o.w = fmaxf(aj.w + bb.w, 0.f);            \
    ((float4*)(h2 + (size_t)(r0 + j) * H2))[tid] = o;
    STORE_ROW(0, a0)
    STORE_ROW(1, a1)
    STORE_ROW(2, a2)
    STORE_ROW(3, a3)
#undef STORE_ROW
}

// ---------------------------------------------------------------------------
// Kernel 3: out = h2 @ Wout + bout   [1024,512] @ [512,20]
// Thread (r, c) with c = tid&31 (active c<20) dots 512. Wout (40 KB) is
// L1/L2 resident; h2 row reads are broadcast within the 32-thread group.
// ---------------------------------------------------------------------------
__global__ __launch_bounds__(256) void k3_out(
    const float* __restrict__ h2, const float* __restrict__ Wout,
    const float* __restrict__ bout, float* __restrict__ out) {
    const int gid = blockIdx.x * 256 + threadIdx.x;
    const int r = gid >> 5;
    const int c = gid & 31;
    if (r >= BATCH || c >= NC) return;

    float acc = bout[c];
    const float* __restrict__ hrow = h2 + (size_t)r * H2;
#pragma unroll 8
    for (int k = 0; k < H2; ++k)
        acc += hrow[k] * Wout[k * NC + c];
    out[r * NC + c] = acc;
}

extern "C" void kernel_launch(void* const* d_in, const int* in_sizes, int n_in,
                              void* d_out, int out_size, void* d_ws, size_t ws_size,
                              hipStream_t stream) {
    const int*   x    = (const int*)d_in[0];
    const float* W1   = (const float*)d_in[1];
    const float* b1   = (const float*)d_in[2];
    const float* W2   = (const float*)d_in[3];
    const float* b2   = (const float*)d_in[4];
    const float* Wout = (const float*)d_in[5];
    const float* bout = (const float*)d_in[6];
    float* out = (float*)d_out;

    float* h1 = (float*)d_ws;                          // 1024*1024*4 = 4 MB
    float* h2 = h1 + (size_t)BATCH * H1;               // 1024*512*4  = 2 MB

    k1_gather_sum<<<BATCH, 256, 0, stream>>>(x, W1, b1, h1);
    k2_gemm_relu<<<BATCH / 4, 128, 0, stream>>>(h1, W2, b2, h2);
    k3_out<<<BATCH * 32 / 256, 256, 0, stream>>>(h2, Wout, bout, out);
}

// Round 2
// 349.368 us; speedup vs baseline: 1.1323x; 1.1323x over previous
//
#include <hip/hip_runtime.h>

#define VOCAB 50257
#define BATCH 1024
#define SEQ   512
#define H1    1024
#define H2    512
#define NC    20

// ---------------------------------------------------------------------------
// Kernel 1: partial gather-sum.
//   p[s][row][0..1023] = sum over token chunk s of W1[x[row, chunk]]
// grid = BATCH*SSPLIT blocks of 256 threads; each thread owns one float4
// column slot. SSPLIT=2 -> 2048 blocks = 8 blocks/CU = 32 waves/CU (full).
// Bias/relu deferred to k2 staging.
// ---------------------------------------------------------------------------
template<int SSPLIT>
__global__ __launch_bounds__(256) void k1_gather(
    const int* __restrict__ x, const float* __restrict__ W1,
    float* __restrict__ p) {
    const int row = blockIdx.x / SSPLIT;
    const int s   = blockIdx.x % SSPLIT;
    const int tid = threadIdx.x;
    constexpr int TOK = SEQ / SSPLIT;

    __shared__ int toks[TOK];
    for (int i = tid; i < TOK; i += 256) toks[i] = x[row * SEQ + s * TOK + i];
    __syncthreads();

    float4 acc = make_float4(0.f, 0.f, 0.f, 0.f);
#pragma unroll 8
    for (int t = 0; t < TOK; ++t) {
        const float4 w = ((const float4*)(W1 + (size_t)toks[t] * H1))[tid];
        acc.x += w.x; acc.y += w.y; acc.z += w.z; acc.w += w.w;
    }
    ((float4*)p)[((size_t)s * BATCH + row) * (H1 / 4) + tid] = acc;
}

// ---------------------------------------------------------------------------
// Kernel 2: h2 = relu( relu(p0[+p1]+b1) @ W2 + b2 )
// Tiles: 16 rows x 128 cols per block, 256 threads = 32 col-quads x 8 K-segs.
// A-tile (16x1024, relu'd) staged in 64KB LDS; K-partials tree-reduced in
// LDS (aliased onto A buffer after main loop). W2 L2-level traffic:
// 256 blocks x 512KB = 128MB (vs 537MB before); HBM-level ~2MB.
// ---------------------------------------------------------------------------
template<int NPART>
__global__ __launch_bounds__(256) void k2_gemm(
    const float* __restrict__ p, const float* __restrict__ b1,
    const float* __restrict__ W2, const float* __restrict__ b2,
    float* __restrict__ h2) {
    __shared__ float As[16][H1];                   // 64 KB
    const int tid = threadIdx.x;
    const int rt  = blockIdx.x >> 2;               // 64 row tiles
    const int ct  = blockIdx.x & 3;                // 4 col tiles of 128
    const int r0  = rt * 16;

    const float* __restrict__ p1 = p + (size_t)BATCH * H1;

    // stage A^(relu) : 4096 float4 elems, 16 iters, coalesced
    for (int i = tid; i < 16 * (H1 / 4); i += 256) {
        const int r  = i >> 8;                     // 256 float4 per row
        const int k4 = i & 255;
        float4 v = ((const float4*)(p + ((size_t)(r0 + r)) * H1))[k4];
        if (NPART == 2) {
            const float4 u = ((const float4*)(p1 + ((size_t)(r0 + r)) * H1))[k4];
            v.x += u.x; v.y += u.y; v.z += u.z; v.w += u.w;
        }
        const float4 bb = ((const float4*)b1)[k4];
        As[r][k4 * 4 + 0] = fmaxf(v.x + bb.x, 0.f);
        As[r][k4 * 4 + 1] = fmaxf(v.y + bb.y, 0.f);
        As[r][k4 * 4 + 2] = fmaxf(v.z + bb.z, 0.f);
        As[r][k4 * 4 + 3] = fmaxf(v.w + bb.w, 0.f);
    }
    __syncthreads();

    const int q  = tid & 31;                       // col quad within tile
    const int ks = tid >> 5;                       // K segment (8 x 128)

    float4 acc[16];
#pragma unroll
    for (int r = 0; r < 16; ++r) acc[r] = make_float4(0.f, 0.f, 0.f, 0.f);

    const float* __restrict__ w2base = W2 + (size_t)ct * 128 + q * 4;
#pragma unroll 2
    for (int kk = 0; kk < 128; ++kk) {
        const int k = ks * 128 + kk;
        const float4 w = *(const float4*)(w2base + (size_t)k * H2);
#pragma unroll
        for (int r = 0; r < 16; ++r) {
            const float a = As[r][k];              // broadcast read
            acc[r].x += a * w.x; acc[r].y += a * w.y;
            acc[r].z += a * w.z; acc[r].w += a * w.w;
        }
    }

    // K-segment tree reduce; alias reduce buffer onto As (done with it)
    __syncthreads();
    float4* Rs = (float4*)As;                      // Rs[(rs*32+q)*16 + r], 32KB max
#define RS(rs, r) Rs[(((rs) * 32 + q) * 16) + (r)]
    if (ks >= 4) {
#pragma unroll
        for (int r = 0; r < 16; ++r) RS(ks - 4, r) = acc[r];
    }
    __syncthreads();
    if (ks < 4) {
#pragma unroll
        for (int r = 0; r < 16; ++r) {
            const float4 t = RS(ks, r);
            acc[r].x += t.x; acc[r].y += t.y; acc[r].z += t.z; acc[r].w += t.w;
        }
    }
    __syncthreads();
    if (ks == 2 || ks == 3) {
#pragma unroll
        for (int r = 0; r < 16; ++r) RS(ks - 2, r) = acc[r];
    }
    __syncthreads();
    if (ks < 2) {
#pragma unroll
        for (int r = 0; r < 16; ++r) {
            const float4 t = RS(ks, r);
            acc[r].x += t.x; acc[r].y += t.y; acc[r].z += t.z; acc[r].w += t.w;
        }
    }
    __syncthreads();
    if (ks == 1) {
#pragma unroll
        for (int r = 0; r < 16; ++r) RS(0, r) = acc[r];
    }
    __syncthreads();
    if (ks == 0) {
        const float4 bb = *(const float4*)(b2 + ct * 128 + q * 4);
#pragma unroll
        for (int r = 0; r < 16; ++r) {
            const float4 t = RS(0, r);
            float4 o;
            o.x = fmaxf(acc[r].x + t.x + bb.x, 0.f);
            o.y = fmaxf(acc[r].y + t.y + bb.y, 0.f);
            o.z = fmaxf(acc[r].z + t.z + bb.z, 0.f);
            o.w = fmaxf(acc[r].w + t.w + bb.w, 0.f);
            *(float4*)(h2 + (size_t)(r0 + r) * H2 + ct * 128 + q * 4) = o;
        }
    }
#undef RS
}

// ---------------------------------------------------------------------------
// Kernel 3: out = h2 @ Wout + bout   [1024,512] @ [512,20]
// ---------------------------------------------------------------------------
__global__ __launch_bounds__(256) void k3_out(
    const float* __restrict__ h2, const float* __restrict__ Wout,
    const float* __restrict__ bout, float* __restrict__ out) {
    const int gid = blockIdx.x * 256 + threadIdx.x;
    const int r = gid >> 5;
    const int c = gid & 31;
    if (c >= NC) return;

    float acc = bout[c];
    const float* __restrict__ hrow = h2 + (size_t)r * H2;
#pragma unroll 8
    for (int k = 0; k < H2; ++k)
        acc += hrow[k] * Wout[k * NC + c];
    out[r * NC + c] = acc;
}

extern "C" void kernel_launch(void* const* d_in, const int* in_sizes, int n_in,
                              void* d_out, int out_size, void* d_ws, size_t ws_size,
                              hipStream_t stream) {
    const int*   x    = (const int*)d_in[0];
    const float* W1   = (const float*)d_in[1];
    const float* b1   = (const float*)d_in[2];
    const float* W2   = (const float*)d_in[3];
    const float* b2   = (const float*)d_in[4];
    const float* Wout = (const float*)d_in[5];
    const float* bout = (const float*)d_in[6];
    float* out = (float*)d_out;

    const size_t need2 = ((size_t)2 * BATCH * H1 + (size_t)BATCH * H2) * 4;

    if (ws_size >= need2) {
        // p: 2 x [1024][1024] partials (8 MB), then h2 (2 MB)
        float* p  = (float*)d_ws;
        float* h2 = p + (size_t)2 * BATCH * H1;
        k1_gather<2><<<BATCH * 2, 256, 0, stream>>>(x, W1, p);
        k2_gemm<2><<<256, 256, 0, stream>>>(p, b1, W2, b2, h2);
        k3_out<<<BATCH * 32 / 256, 256, 0, stream>>>(h2, Wout, bout, out);
    } else {
        float* p  = (float*)d_ws;
        float* h2 = p + (size_t)BATCH * H1;
        k1_gather<1><<<BATCH, 256, 0, stream>>>(x, W1, p);
        k2_gemm<1><<<256, 256, 0, stream>>>(p, b1, W2, b2, h2);
        k3_out<<<BATCH * 32 / 256, 256, 0, stream>>>(h2, Wout, bout, out);
    }
}